// Round 2
// baseline (5682.619 us; speedup 1.0000x reference)
//
#include <hip/hip_runtime.h>
#include <hip/hip_bf16.h>
#include <math.h>

typedef __hip_bfloat16 bf16;

#define Bn  32
#define Cn  160
#define Hn  56
#define Wn  56
#define HWn 3136
#define Pn  100352   // Bn*HWn; 3136 % 64 == 0 so 64-pos tiles never cross images

__device__ __forceinline__ float b2f(bf16 v){ return __bfloat162float(v); }
__device__ __forceinline__ bf16  f2b(float v){ return __float2bfloat16(v); }
__device__ __forceinline__ float gelu_f(float x){ return 0.5f*x*(1.0f + erff(x*0.7071067811865476f)); }

// ---------------- K1: x (NCHW fp32) -> hT = gelu(bn1(x)) (BHWC bf16) ----------------
__global__ __launch_bounds__(256) void k1_bn_gelu_tr(const float* __restrict__ x,
    const float* __restrict__ g, const float* __restrict__ b,
    const float* __restrict__ m, const float* __restrict__ v,
    bf16* __restrict__ hT)
{
    __shared__ float tile[64*161];   // [p][c], stride 161
    __shared__ float sc[160], sh[160];
    int blk = blockIdx.x; int bb = blk/49; int hw0 = (blk - bb*49)*64;
    int tid = threadIdx.x;
    if (tid < 160){
        float s = g[tid] * rsqrtf(v[tid] + 1e-5f);
        sc[tid] = s; sh[tid] = b[tid] - m[tid]*s;
    }
    __syncthreads();
    const float* xb = x + (size_t)bb*Cn*HWn + hw0;
    for (int idx = tid; idx < 160*64; idx += 256){
        int c = idx >> 6, p = idx & 63;
        float val = xb[(size_t)c*HWn + p];
        val = val*sc[c] + sh[c];
        tile[p*161 + c] = gelu_f(val);
    }
    __syncthreads();
    bf16* ho = hT + ((size_t)bb*HWn + hw0)*Cn;
    for (int idx = tid; idx < 64*160; idx += 256){
        int p = idx/160, c = idx - p*160;
        ho[(size_t)p*Cn + c] = f2b(tile[p*161 + c]);
    }
}

// ---------------- K2: 5x conv1x1 (K=160 -> 160 outs, grouped weights) ----------------
__global__ __launch_bounds__(256) void k2_conv5(const bf16* __restrict__ hT,
    const float* __restrict__ w0, const float* __restrict__ b0,
    const float* __restrict__ w1, const float* __restrict__ b1,
    const float* __restrict__ w2, const float* __restrict__ b2,
    const float* __restrict__ w3, const float* __restrict__ b3,
    const float* __restrict__ w4, const float* __restrict__ b4,
    bf16* __restrict__ y5T)
{
    __shared__ float As[64*161];
    __shared__ bf16  Ws[40*160];
    __shared__ float bias_s[40];
    float* Es = (float*)Ws;           // 3200 floats capacity; need 64*41=2624
    int tid = threadIdx.x; int po = tid & 31, oi = tid >> 5;
    size_t pos0 = (size_t)blockIdx.x * 64;
    const bf16* ha = hT + pos0*160;
    for (int idx = tid; idx < 64*160; idx += 256){
        int p = idx/160, k = idx - p*160;
        As[p*161 + k] = b2f(ha[idx]);
    }
    for (int ch = 0; ch < 4; ++ch){
        __syncthreads();
        for (int idx = tid; idx < 40*160; idx += 256){
            int ol = idx/160, k = idx - ol*160;
            int o = ch*40 + ol; int gi = o >> 5, oo = o & 31;
            const float* wp = gi==0?w0: gi==1?w1: gi==2?w2: gi==3?w3: w4;
            Ws[ol*160 + k] = f2b(wp[(size_t)oo*160 + k]);
        }
        if (tid < 40){
            int o = ch*40 + tid; int gi = o >> 5, oo = o & 31;
            const float* bp = gi==0?b0: gi==1?b1: gi==2?b2: gi==3?b3: b4;
            bias_s[tid] = bp[oo];
        }
        __syncthreads();
        float acc[2][5] = {};
        const float* ab = As + po*2*161;
        const bf16*  wb = Ws + oi*5*160;
        for (int k = 0; k < 160; ++k){
            float a0 = ab[k], a1 = ab[161+k];
            #pragma unroll
            for (int j = 0; j < 5; ++j){
                float wv = b2f(wb[j*160 + k]);
                acc[0][j] += a0*wv; acc[1][j] += a1*wv;
            }
        }
        __syncthreads();
        #pragma unroll
        for (int r = 0; r < 2; ++r)
            #pragma unroll
            for (int j = 0; j < 5; ++j)
                Es[(po*2+r)*41 + oi*5+j] = acc[r][j] + bias_s[oi*5+j];
        __syncthreads();
        bf16* yo = y5T + pos0*160 + ch*40;
        for (int idx = tid; idx < 64*40; idx += 256){
            int p = idx/40, ol = idx - p*40;
            yo[(size_t)p*160 + ol] = f2b(Es[p*41 + ol]);
        }
    }
}

// ---------------- K3: shift-gather + wf1 GEMM + bn2 + gelu -> gT ----------------
__global__ __launch_bounds__(256) void k3_wf1(const bf16* __restrict__ y5T,
    const float* __restrict__ wf1, const float* __restrict__ bf1,
    const float* __restrict__ g2, const float* __restrict__ b2v,
    const float* __restrict__ m2, const float* __restrict__ v2,
    bf16* __restrict__ gT)
{
    __shared__ float As[64*161];
    __shared__ bf16  Ws[40*160];
    __shared__ float eps_s[40], ept_s[40];
    float* Es = (float*)Ws;
    int blk = blockIdx.x; int bb = blk/49; int hw0 = (blk - bb*49)*64;
    size_t pos0 = (size_t)bb*HWn + hw0;
    int tid = threadIdx.x; int po = tid & 31, oi = tid >> 5;
    for (int idx = tid; idx < 64*160; idx += 256){
        int p = idx/160, k = idx - p*160;
        int hw = hw0 + p; int h = hw/56, w = hw - h*56;
        int grp = k >> 5;
        int h2 = h, w2 = w; bool ok = true;
        if (grp == 0){ h2 = h+1; ok = (h2 < 56); }        // t: shift from below
        else if (grp == 1){ h2 = h-1; ok = (h2 >= 0); }   // b
        else if (grp == 2){ w2 = w-1; ok = (w2 >= 0); }   // r
        else if (grp == 3){ w2 = w+1; ok = (w2 < 56); }   // l
        float val = 0.f;
        if (ok) val = b2f(y5T[((size_t)bb*HWn + h2*56 + w2)*160 + k]);
        As[p*161 + k] = val;
    }
    for (int ch = 0; ch < 4; ++ch){
        __syncthreads();
        for (int idx = tid; idx < 40*160; idx += 256){
            int ol = idx/160, k = idx - ol*160;
            Ws[ol*160 + k] = f2b(wf1[(size_t)(ch*40 + ol)*160 + k]);
        }
        if (tid < 40){
            int o = ch*40 + tid;
            float s = g2[o] * rsqrtf(v2[o] + 1e-5f);
            eps_s[tid] = s;
            ept_s[tid] = (bf1[o] - m2[o])*s + b2v[o];
        }
        __syncthreads();
        float acc[2][5] = {};
        const float* ab = As + po*2*161;
        const bf16*  wb = Ws + oi*5*160;
        for (int k = 0; k < 160; ++k){
            float a0 = ab[k], a1 = ab[161+k];
            #pragma unroll
            for (int j = 0; j < 5; ++j){
                float wv = b2f(wb[j*160 + k]);
                acc[0][j] += a0*wv; acc[1][j] += a1*wv;
            }
        }
        __syncthreads();
        #pragma unroll
        for (int r = 0; r < 2; ++r)
            #pragma unroll
            for (int j = 0; j < 5; ++j)
                Es[(po*2+r)*41 + oi*5+j] = gelu_f(acc[r][j]*eps_s[oi*5+j] + ept_s[oi*5+j]);
        __syncthreads();
        bf16* go = gT + pos0*160 + ch*40;
        for (int idx = tid; idx < 64*40; idx += 256){
            int p = idx/40, ol = idx - p*40;
            go[(size_t)p*160 + ol] = f2b(Es[p*41 + ol]);
        }
    }
}

// ---------------- K4: proj_h  xhT[b,h,v,c] = sum_w wph[v,w] g[b,h,w,c] + bph[v] ----------------
__global__ __launch_bounds__(256) void k4_projh(const bf16* __restrict__ gT,
    const float* __restrict__ wph, const float* __restrict__ bph, bf16* __restrict__ xhT)
{
    __shared__ float As[56*160];
    __shared__ float Wp[56*56];
    __shared__ float bs[56];
    float* Es = As;
    int blk = blockIdx.x; int bb = blk/56, h = blk - bb*56;
    int tid = threadIdx.x; int ci = tid & 31, vi = tid >> 5;
    const bf16* ga = gT + ((size_t)bb*HWn + h*56)*160;
    for (int idx = tid; idx < 56*160; idx += 256) As[idx] = b2f(ga[idx]);
    for (int idx = tid; idx < 3136; idx += 256) Wp[idx] = wph[idx];
    if (tid < 56) bs[tid] = bph[tid];
    __syncthreads();
    float acc[7][5] = {};
    for (int k = 0; k < 56; ++k){
        float a[5];
        #pragma unroll
        for (int j = 0; j < 5; ++j) a[j] = As[k*160 + ci*5 + j];
        #pragma unroll
        for (int r = 0; r < 7; ++r){
            float wv = Wp[(vi*7+r)*56 + k];
            #pragma unroll
            for (int j = 0; j < 5; ++j) acc[r][j] += wv*a[j];
        }
    }
    __syncthreads();
    #pragma unroll
    for (int r = 0; r < 7; ++r)
        #pragma unroll
        for (int j = 0; j < 5; ++j)
            Es[(vi*7+r)*160 + ci*5+j] = acc[r][j] + bs[vi*7+r];
    __syncthreads();
    bf16* xo = xhT + ((size_t)bb*HWn + h*56)*160;
    for (int idx = tid; idx < 56*160; idx += 256) xo[idx] = f2b(Es[idx]);
}

// ---------------- K5: proj_w  xwT[b,u,w,c] = sum_h wpw[u,h] g[b,h,w,c] + bpw[u] ----------------
__global__ __launch_bounds__(256) void k5_projw(const bf16* __restrict__ gT,
    const float* __restrict__ wpw, const float* __restrict__ bpw, bf16* __restrict__ xwT)
{
    __shared__ float As[56*160];
    __shared__ float Wp[56*56];
    __shared__ float bs[56];
    float* Es = As;
    int blk = blockIdx.x; int bb = blk/56, w = blk - bb*56;
    int tid = threadIdx.x; int ci = tid & 31, vi = tid >> 5;
    const bf16* gbase = gT + ((size_t)bb*HWn + w)*160;
    for (int idx = tid; idx < 56*160; idx += 256){
        int hh = idx/160, c = idx - hh*160;
        As[idx] = b2f(gbase[(size_t)hh*56*160 + c]);
    }
    for (int idx = tid; idx < 3136; idx += 256) Wp[idx] = wpw[idx];
    if (tid < 56) bs[tid] = bpw[tid];
    __syncthreads();
    float acc[7][5] = {};
    for (int k = 0; k < 56; ++k){
        float a[5];
        #pragma unroll
        for (int j = 0; j < 5; ++j) a[j] = As[k*160 + ci*5 + j];
        #pragma unroll
        for (int r = 0; r < 7; ++r){
            float wv = Wp[(vi*7+r)*56 + k];
            #pragma unroll
            for (int j = 0; j < 5; ++j) acc[r][j] += wv*a[j];
        }
    }
    __syncthreads();
    #pragma unroll
    for (int r = 0; r < 7; ++r)
        #pragma unroll
        for (int j = 0; j < 5; ++j)
            Es[(vi*7+r)*160 + ci*5+j] = acc[r][j] + bs[vi*7+r];
    __syncthreads();
    bf16* xo = xwT + ((size_t)bb*HWn + w)*160;
    for (int idx = tid; idx < 56*160; idx += 256){
        int u = idx/160, c = idx - u*160;
        xo[(size_t)u*56*160 + c] = f2b(Es[idx]);
    }
}

// ---------------- K6: wf2 GEMM over concat(g,xh,xw) K=480, + x residual -> x1 (NCHW fp32) ------
__global__ __launch_bounds__(256) void k6_wf2(const bf16* __restrict__ gT,
    const bf16* __restrict__ xhT, const bf16* __restrict__ xwT,
    const float* __restrict__ wf2, const float* __restrict__ x, float* __restrict__ x1)
{
    __shared__ float As[64*161];
    __shared__ bf16  Ws[40*160];
    float* Es = (float*)Ws;
    int blk = blockIdx.x; int bb = blk/49; int hw0 = (blk - bb*49)*64;
    size_t pos0 = (size_t)bb*HWn + hw0;
    int tid = threadIdx.x; int po = tid & 31, oi = tid >> 5;
    float acc[4][2][5] = {};
    for (int kc = 0; kc < 3; ++kc){
        __syncthreads();
        const bf16* sa = (kc==0 ? gT : (kc==1 ? xhT : xwT)) + pos0*160;
        for (int idx = tid; idx < 64*160; idx += 256){
            int p = idx/160, k = idx - p*160;
            As[p*161 + k] = b2f(sa[idx]);
        }
        for (int ch = 0; ch < 4; ++ch){
            __syncthreads();
            for (int idx = tid; idx < 40*160; idx += 256){
                int ol = idx/160, k = idx - ol*160;
                Ws[ol*160 + k] = f2b(wf2[(size_t)(ch*40 + ol)*480 + kc*160 + k]);
            }
            __syncthreads();
            const float* ab = As + po*2*161;
            const bf16*  wb = Ws + oi*5*160;
            for (int k = 0; k < 160; ++k){
                float a0 = ab[k], a1 = ab[161+k];
                #pragma unroll
                for (int j = 0; j < 5; ++j){
                    float wv = b2f(wb[j*160 + k]);
                    acc[ch][0][j] += a0*wv; acc[ch][1][j] += a1*wv;
                }
            }
        }
    }
    const float* xr = x  + (size_t)bb*Cn*HWn + hw0;
    float*       xo = x1 + (size_t)bb*Cn*HWn + hw0;
    for (int ch = 0; ch < 4; ++ch){
        __syncthreads();
        #pragma unroll
        for (int r = 0; r < 2; ++r)
            #pragma unroll
            for (int j = 0; j < 5; ++j)
                Es[(po*2+r)*41 + oi*5+j] = acc[ch][r][j];
        __syncthreads();
        for (int idx = tid; idx < 40*64; idx += 256){
            int ol = idx >> 6, p = idx & 63;
            int o = ch*40 + ol;
            xo[(size_t)o*HWn + p] = Es[p*41 + ol] + xr[(size_t)o*HWn + p];
        }
    }
}

// ---------------- K7: LN over C + fc1 (160->480) + gelu -> u (bf16, [pos][480]) ----------------
__global__ __launch_bounds__(256) void k7_ln_fc1(const float* __restrict__ x1,
    const float* __restrict__ lng, const float* __restrict__ lnb,
    const float* __restrict__ wfc1, const float* __restrict__ bfc1, bf16* __restrict__ u)
{
    __shared__ float As[64*161];
    __shared__ bf16  Ws[40*160];
    __shared__ float lg[160], lb[160], bias_s[40];
    float* Es = (float*)Ws;
    int blk = blockIdx.x; int bb = blk/49; int hw0 = (blk - bb*49)*64;
    size_t pos0 = (size_t)bb*HWn + hw0;
    int tid = threadIdx.x; int po = tid & 31, oi = tid >> 5;
    const float* xa = x1 + (size_t)bb*Cn*HWn + hw0;
    for (int idx = tid; idx < 160*64; idx += 256){
        int c = idx >> 6, p = idx & 63;
        As[p*161 + c] = xa[(size_t)c*HWn + p];
    }
    if (tid < 160){ lg[tid] = lng[tid]; lb[tid] = lnb[tid]; }
    __syncthreads();
    {
        int p = tid >> 2, q = tid & 3;
        float s = 0.f, ss = 0.f;
        const float* row = As + p*161;
        for (int c = q*40; c < q*40 + 40; ++c){ float vv = row[c]; s += vv; ss += vv*vv; }
        s  += __shfl_xor(s, 1);  ss += __shfl_xor(ss, 1);
        s  += __shfl_xor(s, 2);  ss += __shfl_xor(ss, 2);
        float mean = s * (1.f/160.f);
        float var  = ss * (1.f/160.f) - mean*mean;
        float rstd = rsqrtf(var + 1e-5f);
        for (int c = q*40; c < q*40 + 40; ++c){
            float vv = row[c];
            As[p*161 + c] = (vv - mean)*rstd*lg[c] + lb[c];
        }
    }
    for (int ch = 0; ch < 12; ++ch){
        __syncthreads();
        for (int idx = tid; idx < 40*160; idx += 256){
            int ol = idx/160, k = idx - ol*160;
            Ws[ol*160 + k] = f2b(wfc1[(size_t)(ch*40 + ol)*160 + k]);
        }
        if (tid < 40) bias_s[tid] = bfc1[ch*40 + tid];
        __syncthreads();
        float acc[2][5] = {};
        const float* ab = As + po*2*161;
        const bf16*  wb = Ws + oi*5*160;
        for (int k = 0; k < 160; ++k){
            float a0 = ab[k], a1 = ab[161+k];
            #pragma unroll
            for (int j = 0; j < 5; ++j){
                float wv = b2f(wb[j*160 + k]);
                acc[0][j] += a0*wv; acc[1][j] += a1*wv;
            }
        }
        __syncthreads();
        #pragma unroll
        for (int r = 0; r < 2; ++r)
            #pragma unroll
            for (int j = 0; j < 5; ++j)
                Es[(po*2+r)*41 + oi*5+j] = gelu_f(acc[r][j] + bias_s[oi*5+j]);
        __syncthreads();
        bf16* uo = u + pos0*480 + ch*40;
        for (int idx = tid; idx < 64*40; idx += 256){
            int p = idx/40, ol = idx - p*40;
            uo[(size_t)p*480 + ol] = f2b(Es[p*41 + ol]);
        }
    }
}

// ---------------- K8: fc2 (480->160) + bfc2 + x1 residual -> out (NCHW fp32) ----------------
__global__ __launch_bounds__(256) void k8_fc2(const bf16* __restrict__ u,
    const float* __restrict__ wfc2, const float* __restrict__ bfc2,
    const float* __restrict__ x1, float* __restrict__ out)
{
    __shared__ float As[64*161];
    __shared__ bf16  Ws[40*160];
    __shared__ float bias_s[160];
    float* Es = (float*)Ws;
    int blk = blockIdx.x; int bb = blk/49; int hw0 = (blk - bb*49)*64;
    size_t pos0 = (size_t)bb*HWn + hw0;
    int tid = threadIdx.x; int po = tid & 31, oi = tid >> 5;
    if (tid < 160) bias_s[tid] = bfc2[tid];
    float acc[4][2][5] = {};
    for (int kc = 0; kc < 3; ++kc){
        __syncthreads();
        const bf16* ua = u + pos0*480 + kc*160;
        for (int idx = tid; idx < 64*160; idx += 256){
            int p = idx/160, k = idx - p*160;
            As[p*161 + k] = b2f(ua[(size_t)p*480 + k]);
        }
        for (int ch = 0; ch < 4; ++ch){
            __syncthreads();
            for (int idx = tid; idx < 40*160; idx += 256){
                int ol = idx/160, k = idx - ol*160;
                Ws[ol*160 + k] = f2b(wfc2[(size_t)(ch*40 + ol)*480 + kc*160 + k]);
            }
            __syncthreads();
            const float* ab = As + po*2*161;
            const bf16*  wb = Ws + oi*5*160;
            for (int k = 0; k < 160; ++k){
                float a0 = ab[k], a1 = ab[161+k];
                #pragma unroll
                for (int j = 0; j < 5; ++j){
                    float wv = b2f(wb[j*160 + k]);
                    acc[ch][0][j] += a0*wv; acc[ch][1][j] += a1*wv;
                }
            }
        }
    }
    const float* xr = x1 + (size_t)bb*Cn*HWn + hw0;
    float*       oo = out + (size_t)bb*Cn*HWn + hw0;
    for (int ch = 0; ch < 4; ++ch){
        __syncthreads();
        #pragma unroll
        for (int r = 0; r < 2; ++r)
            #pragma unroll
            for (int j = 0; j < 5; ++j)
                Es[(po*2+r)*41 + oi*5+j] = acc[ch][r][j] + bias_s[ch*40 + oi*5+j];
        __syncthreads();
        for (int idx = tid; idx < 40*64; idx += 256){
            int ol = idx >> 6, p = idx & 63;
            int o = ch*40 + ol;
            oo[(size_t)o*HWn + p] = Es[p*41 + ol] + xr[(size_t)o*HWn + p];
        }
    }
}

extern "C" void kernel_launch(void* const* d_in, const int* in_sizes, int n_in,
                              void* d_out, int out_size, void* d_ws, size_t ws_size,
                              hipStream_t stream)
{
    (void)in_sizes; (void)n_in; (void)out_size; (void)ws_size;
    const float* x     = (const float*)d_in[0];
    const float* bn1g  = (const float*)d_in[1];
    const float* bn1b  = (const float*)d_in[2];
    const float* bn1m  = (const float*)d_in[3];
    const float* bn1v  = (const float*)d_in[4];
    const float* wt    = (const float*)d_in[5];
    const float* bt    = (const float*)d_in[6];
    const float* wb    = (const float*)d_in[7];
    const float* bb    = (const float*)d_in[8];
    const float* wr    = (const float*)d_in[9];
    const float* br    = (const float*)d_in[10];
    const float* wl    = (const float*)d_in[11];
    const float* bl    = (const float*)d_in[12];
    const float* wc    = (const float*)d_in[13];
    const float* bc    = (const float*)d_in[14];
    const float* wf1   = (const float*)d_in[15];
    const float* bf1   = (const float*)d_in[16];
    const float* bn2g  = (const float*)d_in[17];
    const float* bn2b  = (const float*)d_in[18];
    const float* bn2m  = (const float*)d_in[19];
    const float* bn2v  = (const float*)d_in[20];
    const float* wph   = (const float*)d_in[21];
    const float* bph   = (const float*)d_in[22];
    const float* wpw   = (const float*)d_in[23];
    const float* bpw   = (const float*)d_in[24];
    const float* wf2   = (const float*)d_in[25];
    const float* lng   = (const float*)d_in[26];
    const float* lnb   = (const float*)d_in[27];
    const float* wfc1  = (const float*)d_in[28];
    const float* bfc1  = (const float*)d_in[29];
    const float* wfc2  = (const float*)d_in[30];
    const float* bfc2v = (const float*)d_in[31];
    // d_in[32] = step (int, ==1) — shifts hardcoded for step=1.
    float* outp = (float*)d_out;

    // workspace layout; PC = Pn*160 = 16,056,320 elements
    const size_t PC2 = (size_t)Pn*160*2;       // 32,112,640 B per bf16 buffer
    char* ws = (char*)d_ws;
    bf16*  hT  = (bf16*)(ws + 0*PC2);
    bf16*  y5T = (bf16*)(ws + 1*PC2);
    bf16*  gT  = (bf16*)(ws + 2*PC2);
    bf16*  xhT = (bf16*)(ws + 3*PC2);
    bf16*  xwT = (bf16*)(ws + 4*PC2);
    float* x1  = (float*)(ws + 5*PC2);         // fp32, 64,225,280 B
    bf16*  uB  = (bf16*)(ws + 0);              // [Pn][480] bf16 = 96,337,920 B, reuses hT/y5T/gT (dead)
    // total ws: 5*PC2 + Pn*160*4 = 224,788,480 B

    const int GP = Pn/64;      // 1568
    const int GS = Bn*Hn;      // 1792

    k1_bn_gelu_tr<<<GP, 256, 0, stream>>>(x, bn1g, bn1b, bn1m, bn1v, hT);
    k2_conv5     <<<GP, 256, 0, stream>>>(hT, wt, bt, wb, bb, wr, br, wl, bl, wc, bc, y5T);
    k3_wf1       <<<GP, 256, 0, stream>>>(y5T, wf1, bf1, bn2g, bn2b, bn2m, bn2v, gT);
    k4_projh     <<<GS, 256, 0, stream>>>(gT, wph, bph, xhT);
    k5_projw     <<<GS, 256, 0, stream>>>(gT, wpw, bpw, xwT);
    k6_wf2       <<<GP, 256, 0, stream>>>(gT, xhT, xwT, wf2, x, x1);
    k7_ln_fc1    <<<GP, 256, 0, stream>>>(x1, lng, lnb, wfc1, bfc1, uB);
    k8_fc2       <<<GP, 256, 0, stream>>>(uB, wfc2, bfc2v, x1, outp);
}

// Round 3
// 562.020 us; speedup vs baseline: 10.1111x; 10.1111x over previous
//
#include <hip/hip_runtime.h>
#include <hip/hip_bf16.h>
#include <math.h>

typedef __hip_bfloat16 bf16;
typedef __attribute__((ext_vector_type(8))) short s8v;   // 8 bf16 bit-carrier (4 VGPR)
typedef __attribute__((ext_vector_type(4))) float f4v;   // MFMA 16x16 accumulator

#define Bn  32
#define Cn  160
#define HWn 3136
#define Pn  100352

__device__ __forceinline__ float b2f(bf16 v){ return __bfloat162float(v); }
__device__ __forceinline__ bf16  f2b(float v){ return __float2bfloat16(v); }
__device__ __forceinline__ float bits2f(unsigned short u){
    union { float f; unsigned int i; } x; x.i = ((unsigned int)u) << 16; return x.f;
}
__device__ __forceinline__ float gelu_f(float x){ return 0.5f*x*(1.0f + erff(x*0.7071067811865476f)); }

#define MFMA(a,b,c) __builtin_amdgcn_mfma_f32_16x16x32_bf16((a),(b),(c),0,0,0)

// ---------------- K0: weight prep (fp32 -> bf16, concat/pad) ----------------
__global__ __launch_bounds__(256) void k0_prep(
    const float* __restrict__ wt, const float* __restrict__ wb_, const float* __restrict__ wr,
    const float* __restrict__ wl, const float* __restrict__ wc,
    const float* __restrict__ bt, const float* __restrict__ bb_, const float* __restrict__ br,
    const float* __restrict__ bl, const float* __restrict__ bc,
    const float* __restrict__ wf1, const float* __restrict__ bf1,
    const float* __restrict__ g2, const float* __restrict__ b2, const float* __restrict__ m2, const float* __restrict__ v2,
    const float* __restrict__ wf2, const float* __restrict__ wfc1, const float* __restrict__ wfc2,
    const float* __restrict__ wph, const float* __restrict__ wpw,
    bf16* wcat, bf16* wf1b, bf16* wf2b, bf16* wfc1b, bf16* wfc2b, bf16* wphb, bf16* wpwb,
    float* bcat, float* epsv, float* eptv)
{
    int idx = blockIdx.x*256 + threadIdx.x;
    if (idx < 25600){ int o = idx/160, k = idx - o*160; int gi = o>>5, oo = o&31;
        const float* wp = gi==0?wt: gi==1?wb_: gi==2?wr: gi==3?wl: wc;
        wcat[idx] = f2b(wp[oo*160+k]); return; }
    idx -= 25600;
    if (idx < 25600){ wf1b[idx] = f2b(wf1[idx]); return; }
    idx -= 25600;
    if (idx < 76800){ wf2b[idx] = f2b(wf2[idx]); return; }
    idx -= 76800;
    if (idx < 76800){ wfc1b[idx] = f2b(wfc1[idx]); return; }
    idx -= 76800;
    if (idx < 76800){ wfc2b[idx] = f2b(wfc2[idx]); return; }
    idx -= 76800;
    if (idx < 4096){ int v = idx>>6, w = idx&63;
        wphb[idx] = (v<56 && w<56) ? f2b(wph[v*56+w]) : f2b(0.f); return; }
    idx -= 4096;
    if (idx < 4096){ int v = idx>>6, w = idx&63;
        wpwb[idx] = (v<56 && w<56) ? f2b(wpw[v*56+w]) : f2b(0.f); return; }
    idx -= 4096;
    if (idx < 160){ int o = idx; int gi = o>>5, oo = o&31;
        const float* bp = gi==0?bt: gi==1?bb_: gi==2?br: gi==3?bl: bc;
        bcat[o] = bp[oo]; return; }
    idx -= 160;
    if (idx < 160){ int o = idx; float s = g2[o]*rsqrtf(v2[o]+1e-5f);
        epsv[o] = s; eptv[o] = (bf1[o]-m2[o])*s + b2[o]; return; }
}

// ---------------- K1: x (NCHW fp32) -> hT = gelu(bn1(x)) (BHWC bf16) ----------------
__global__ __launch_bounds__(256) void k1_bn_gelu_tr(const float* __restrict__ x,
    const float* __restrict__ g, const float* __restrict__ b,
    const float* __restrict__ m, const float* __restrict__ v,
    bf16* __restrict__ hT)
{
    __shared__ float tile[64*161];
    __shared__ float sc[160], sh[160];
    int blk = blockIdx.x; int bb = blk/49; int hw0 = (blk - bb*49)*64;
    int tid = threadIdx.x;
    if (tid < 160){
        float s = g[tid] * rsqrtf(v[tid] + 1e-5f);
        sc[tid] = s; sh[tid] = b[tid] - m[tid]*s;
    }
    __syncthreads();
    const float* xb = x + (size_t)bb*Cn*HWn + hw0;
    for (int idx = tid; idx < 160*64; idx += 256){
        int c = idx >> 6, p = idx & 63;
        float val = xb[(size_t)c*HWn + p];
        tile[p*161 + c] = gelu_f(val*sc[c] + sh[c]);
    }
    __syncthreads();
    bf16* ho = hT + ((size_t)bb*HWn + hw0)*Cn;
    for (int idx = tid; idx < 64*160; idx += 256){
        int p = idx/160, c = idx - p*160;
        ho[idx] = f2b(tile[p*161 + c]);
    }
}

// ---------------- K2: conv5 GEMM  y5T[pos][o] = hT[pos][:] @ wcat[o][:] + bcat[o] ----------------
__global__ __launch_bounds__(256) void k2_conv5(const bf16* __restrict__ hT,
    const bf16* __restrict__ wcat, const float* __restrict__ bcat, bf16* __restrict__ y5T)
{
    __shared__ __align__(16) unsigned short Bs[2][16*168];
    int tid = threadIdx.x, wave = tid>>6, lane = tid&63, m = lane&15, q = lane>>4;
    size_t pos0 = (size_t)blockIdx.x*64;
    const unsigned short* Ap = (const unsigned short*)hT + (pos0 + wave*16 + m)*160 + q*8;
    s8v a[5];
    #pragma unroll
    for (int kb = 0; kb < 5; ++kb) a[kb] = *(const s8v*)(Ap + kb*32);
    { const s8v* sp = (const s8v*)((const unsigned short*)wcat);
      for (int c = tid; c < 320; c += 256){ int row = c/20, col = (c - row*20)*8;
          *(s8v*)&Bs[0][row*168 + col] = sp[c]; } }
    __syncthreads();
    for (int s = 0; s < 10; ++s){
        if (s+1 < 10){
            const s8v* sp = (const s8v*)((const unsigned short*)wcat + (size_t)(s+1)*2560);
            for (int c = tid; c < 320; c += 256){ int row = c/20, col = (c - row*20)*8;
                *(s8v*)&Bs[(s+1)&1][row*168 + col] = sp[c]; }
        }
        f4v acc = {0.f,0.f,0.f,0.f};
        const unsigned short* Bp = &Bs[s&1][m*168 + q*8];
        #pragma unroll
        for (int kb = 0; kb < 5; ++kb) acc = MFMA(a[kb], *(const s8v*)(Bp + kb*32), acc);
        float bias = bcat[s*16 + m];
        bf16* yo = y5T + (pos0 + wave*16 + q*4)*160 + s*16 + m;
        #pragma unroll
        for (int r = 0; r < 4; ++r) yo[r*160] = f2b(acc[r] + bias);
        __syncthreads();
    }
}

// ---------------- K3: shifted-A GEMM + bn2 + gelu -> gT ----------------
__global__ __launch_bounds__(256) void k3_wf1(const bf16* __restrict__ y5T,
    const bf16* __restrict__ wf1b, const float* __restrict__ epsv, const float* __restrict__ eptv,
    bf16* __restrict__ gT)
{
    __shared__ __align__(16) unsigned short Bs[2][16*168];
    int tid = threadIdx.x, wave = tid>>6, lane = tid&63, m = lane&15, q = lane>>4;
    int blk = blockIdx.x; int bb = blk/49; int hw0 = (blk - bb*49)*64;
    size_t pos0 = (size_t)bb*HWn + hw0;
    int phw = hw0 + wave*16 + m; int h = phw/56, w = phw - h*56;
    s8v a[5];
    #pragma unroll
    for (int kb = 0; kb < 5; ++kb){
        int h2 = h, w2 = w; bool ok = true;
        if      (kb == 0){ h2 = h+1; ok = (h2 < 56); }
        else if (kb == 1){ h2 = h-1; ok = (h2 >= 0); }
        else if (kb == 2){ w2 = w-1; ok = (w2 >= 0); }
        else if (kb == 3){ w2 = w+1; ok = (w2 < 56); }
        if (ok){
            const unsigned short* Ap = (const unsigned short*)y5T +
                ((size_t)bb*HWn + h2*56 + w2)*160 + kb*32 + q*8;
            a[kb] = *(const s8v*)Ap;
        } else {
            a[kb] = (s8v){0,0,0,0,0,0,0,0};
        }
    }
    { const s8v* sp = (const s8v*)((const unsigned short*)wf1b);
      for (int c = tid; c < 320; c += 256){ int row = c/20, col = (c - row*20)*8;
          *(s8v*)&Bs[0][row*168 + col] = sp[c]; } }
    __syncthreads();
    for (int s = 0; s < 10; ++s){
        if (s+1 < 10){
            const s8v* sp = (const s8v*)((const unsigned short*)wf1b + (size_t)(s+1)*2560);
            for (int c = tid; c < 320; c += 256){ int row = c/20, col = (c - row*20)*8;
                *(s8v*)&Bs[(s+1)&1][row*168 + col] = sp[c]; }
        }
        f4v acc = {0.f,0.f,0.f,0.f};
        const unsigned short* Bp = &Bs[s&1][m*168 + q*8];
        #pragma unroll
        for (int kb = 0; kb < 5; ++kb) acc = MFMA(a[kb], *(const s8v*)(Bp + kb*32), acc);
        int o = s*16 + m;
        float es = epsv[o], et = eptv[o];
        bf16* go = gT + (pos0 + wave*16 + q*4)*160 + o;
        #pragma unroll
        for (int r = 0; r < 4; ++r) go[r*160] = f2b(gelu_f(acc[r]*es + et));
        __syncthreads();
    }
}

// ---------------- K4: proj_h MFMA  xhT[b, h*56+v][c] = sum_w wph[v][w] g[b,h*56+w][c] + bph[v] ----
__global__ __launch_bounds__(256) void k4_projh(const bf16* __restrict__ gT,
    const bf16* __restrict__ wphb, const float* __restrict__ bph, bf16* __restrict__ xhT)
{
    __shared__ __align__(16) unsigned short gS[160*72];
    int tid = threadIdx.x, wave = tid>>6, lane = tid&63, m = lane&15, q = lane>>4;
    int blk = blockIdx.x; int b = blk/56, h = blk - b*56;
    const unsigned short* ga = (const unsigned short*)gT + ((size_t)b*HWn + h*56)*160;
    for (int idx = tid; idx < 56*160; idx += 256){
        int w = idx/160, c = idx - w*160;
        gS[c*72 + w] = ga[idx];
    }
    for (int idx = tid; idx < 160*8; idx += 256){
        int c = idx>>3, w = 56 + (idx&7);
        gS[c*72 + w] = 0;
    }
    __syncthreads();
    int v0 = wave*16;
    s8v a[2];
    #pragma unroll
    for (int kb = 0; kb < 2; ++kb)
        a[kb] = *(const s8v*)((const unsigned short*)wphb + (v0+m)*64 + kb*32 + q*8);
    int v = v0 + q*4;
    for (int s = 0; s < 10; ++s){
        f4v acc = {0.f,0.f,0.f,0.f};
        const unsigned short* Bp = &gS[(s*16+m)*72 + q*8];
        #pragma unroll
        for (int kb = 0; kb < 2; ++kb) acc = MFMA(a[kb], *(const s8v*)(Bp + kb*32), acc);
        #pragma unroll
        for (int r = 0; r < 4; ++r){
            int vv = v + r;
            if (vv < 56)
                xhT[((size_t)b*HWn + h*56 + vv)*160 + s*16 + m] = f2b(acc[r] + bph[vv]);
        }
    }
}

// ---------------- K5: proj_w MFMA  xwT[b, v*56+w][c] = sum_h wpw[v][h] g[b,h*56+w][c] + bpw[v] ----
__global__ __launch_bounds__(256) void k5_projw(const bf16* __restrict__ gT,
    const bf16* __restrict__ wpwb, const float* __restrict__ bpw, bf16* __restrict__ xwT)
{
    __shared__ __align__(16) unsigned short gS[160*72];
    int tid = threadIdx.x, wave = tid>>6, lane = tid&63, m = lane&15, q = lane>>4;
    int blk = blockIdx.x; int b = blk/56, w = blk - b*56;
    const unsigned short* gbase = (const unsigned short*)gT + ((size_t)b*HWn + w)*160;
    for (int idx = tid; idx < 56*160; idx += 256){
        int hh = idx/160, c = idx - hh*160;
        gS[c*72 + hh] = gbase[(size_t)hh*56*160 + c];
    }
    for (int idx = tid; idx < 160*8; idx += 256){
        int c = idx>>3, hh = 56 + (idx&7);
        gS[c*72 + hh] = 0;
    }
    __syncthreads();
    int v0 = wave*16;
    s8v a[2];
    #pragma unroll
    for (int kb = 0; kb < 2; ++kb)
        a[kb] = *(const s8v*)((const unsigned short*)wpwb + (v0+m)*64 + kb*32 + q*8);
    int v = v0 + q*4;
    for (int s = 0; s < 10; ++s){
        f4v acc = {0.f,0.f,0.f,0.f};
        const unsigned short* Bp = &gS[(s*16+m)*72 + q*8];
        #pragma unroll
        for (int kb = 0; kb < 2; ++kb) acc = MFMA(a[kb], *(const s8v*)(Bp + kb*32), acc);
        #pragma unroll
        for (int r = 0; r < 4; ++r){
            int vv = v + r;
            if (vv < 56)
                xwT[((size_t)b*HWn + vv*56 + w)*160 + s*16 + m] = f2b(acc[r] + bpw[vv]);
        }
    }
}

// ---------------- K6: wf2 GEMM (K=480 concat) -> gm bf16 BHWC ----------------
__global__ __launch_bounds__(256) void k6_wf2(const bf16* __restrict__ gT,
    const bf16* __restrict__ xhT, const bf16* __restrict__ xwT,
    const bf16* __restrict__ wf2b, bf16* __restrict__ gm)
{
    __shared__ __align__(16) unsigned short Bs[2][16*488];
    int tid = threadIdx.x, wave = tid>>6, lane = tid&63, m = lane&15, q = lane>>4;
    size_t pos0 = (size_t)blockIdx.x*64;
    size_t prow = (pos0 + wave*16 + m)*160;
    s8v a[15];
    #pragma unroll
    for (int kb = 0; kb < 15; ++kb){
        const bf16* src = (kb < 5) ? gT : (kb < 10 ? xhT : xwT);
        int kc = (kb - (kb < 5 ? 0 : (kb < 10 ? 5 : 10)))*32 + q*8;
        a[kb] = *(const s8v*)((const unsigned short*)src + prow + kc);
    }
    { const s8v* sp = (const s8v*)((const unsigned short*)wf2b);
      for (int c = tid; c < 960; c += 256){ int row = c/60, col = (c - row*60)*8;
          *(s8v*)&Bs[0][row*488 + col] = sp[c]; } }
    __syncthreads();
    for (int s = 0; s < 10; ++s){
        if (s+1 < 10){
            const s8v* sp = (const s8v*)((const unsigned short*)wf2b + (size_t)(s+1)*7680);
            for (int c = tid; c < 960; c += 256){ int row = c/60, col = (c - row*60)*8;
                *(s8v*)&Bs[(s+1)&1][row*488 + col] = sp[c]; }
        }
        f4v acc = {0.f,0.f,0.f,0.f};
        const unsigned short* Bp = &Bs[s&1][m*488 + q*8];
        #pragma unroll
        for (int kb = 0; kb < 15; ++kb) acc = MFMA(a[kb], *(const s8v*)(Bp + kb*32), acc);
        bf16* go = gm + (pos0 + wave*16 + q*4)*160 + s*16 + m;
        #pragma unroll
        for (int r = 0; r < 4; ++r) go[r*160] = f2b(acc[r]);
        __syncthreads();
    }
}

// ---------------- K7: LN(x+gm) + fc1 + gelu -> u [pos][480] bf16 ----------------
__global__ __launch_bounds__(256) void k7_ln_fc1(const float* __restrict__ x,
    const bf16* __restrict__ gm,
    const float* __restrict__ lng, const float* __restrict__ lnb,
    const bf16* __restrict__ wfc1b, const float* __restrict__ bfc1, bf16* __restrict__ u)
{
    __shared__ float Xs[64*161];
    __shared__ __align__(16) unsigned short As[64*168];
    __shared__ __align__(16) unsigned short Bs[2][16*168];
    int tid = threadIdx.x, wave = tid>>6, lane = tid&63, m = lane&15, q = lane>>4;
    int blk = blockIdx.x; int bb = blk/49; int hw0 = (blk - bb*49)*64;
    size_t pos0 = (size_t)bb*HWn + hw0;
    const float* xb = x + (size_t)bb*Cn*HWn + hw0;
    for (int idx = tid; idx < 160*64; idx += 256){
        int o = idx >> 6, p = idx & 63;
        Xs[p*161 + o] = xb[(size_t)o*HWn + p];
    }
    { const s8v* sp = (const s8v*)((const unsigned short*)wfc1b);
      for (int c = tid; c < 320; c += 256){ int row = c/20, col = (c - row*20)*8;
          *(s8v*)&Bs[0][row*168 + col] = sp[c]; } }
    __syncthreads();
    {
        int p = tid >> 2, q4 = tid & 3;
        const unsigned short* gp = (const unsigned short*)gm + (pos0 + p)*160 + q4*40;
        float s = 0.f, ss = 0.f;
        #pragma unroll 8
        for (int i = 0; i < 40; ++i){
            int c = q4*40 + i;
            float vv = Xs[p*161 + c] + bits2f(gp[i]);
            Xs[p*161 + c] = vv;
            s += vv; ss += vv*vv;
        }
        s  += __shfl_xor(s, 1);  ss += __shfl_xor(ss, 1);
        s  += __shfl_xor(s, 2);  ss += __shfl_xor(ss, 2);
        float mean = s * (1.f/160.f);
        float var  = ss * (1.f/160.f) - mean*mean;
        float rstd = rsqrtf(var + 1e-5f);
        #pragma unroll 8
        for (int i = 0; i < 40; ++i){
            int c = q4*40 + i;
            float nv = (Xs[p*161 + c] - mean)*rstd*lng[c] + lnb[c];
            union { unsigned short us; bf16 b; } cv; cv.b = f2b(nv);
            As[p*168 + c] = cv.us;
        }
    }
    __syncthreads();
    s8v a[5];
    const unsigned short* Ap = &As[(wave*16 + m)*168 + q*8];
    #pragma unroll
    for (int kb = 0; kb < 5; ++kb) a[kb] = *(const s8v*)(Ap + kb*32);
    for (int s = 0; s < 30; ++s){
        if (s+1 < 30){
            const s8v* sp = (const s8v*)((const unsigned short*)wfc1b + (size_t)(s+1)*2560);
            for (int c = tid; c < 320; c += 256){ int row = c/20, col = (c - row*20)*8;
                *(s8v*)&Bs[(s+1)&1][row*168 + col] = sp[c]; }
        }
        f4v acc = {0.f,0.f,0.f,0.f};
        const unsigned short* Bp = &Bs[s&1][m*168 + q*8];
        #pragma unroll
        for (int kb = 0; kb < 5; ++kb) acc = MFMA(a[kb], *(const s8v*)(Bp + kb*32), acc);
        float bias = bfc1[s*16 + m];
        bf16* uo = u + (pos0 + wave*16 + q*4)*480 + s*16 + m;
        #pragma unroll
        for (int r = 0; r < 4; ++r) uo[r*480] = f2b(gelu_f(acc[r] + bias));
        __syncthreads();
    }
}

// ---------------- K8: fc2 (K=480) + bfc2 + (x+gm) residual -> out NCHW fp32 ----------------
__global__ __launch_bounds__(256) void k8_fc2(const bf16* __restrict__ u,
    const bf16* __restrict__ wfc2b, const float* __restrict__ bfc2,
    const float* __restrict__ x, const bf16* __restrict__ gm, float* __restrict__ out)
{
    __shared__ float Ds[64*161];
    __shared__ __align__(16) unsigned short Bs[2][16*488];
    int tid = threadIdx.x, wave = tid>>6, lane = tid&63, m = lane&15, q = lane>>4;
    int blk = blockIdx.x; int bb = blk/49; int hw0 = (blk - bb*49)*64;
    size_t pos0 = (size_t)bb*HWn + hw0;
    const float* xb = x + (size_t)bb*Cn*HWn + hw0;
    for (int idx = tid; idx < 160*64; idx += 256){
        int o = idx >> 6, p = idx & 63;
        Ds[p*161 + o] = xb[(size_t)o*HWn + p];
    }
    { const s8v* sp = (const s8v*)((const unsigned short*)wfc2b);
      for (int c = tid; c < 960; c += 256){ int row = c/60, col = (c - row*60)*8;
          *(s8v*)&Bs[0][row*488 + col] = sp[c]; } }
    __syncthreads();
    {
        const unsigned short* gp = (const unsigned short*)gm + pos0*160;
        for (int idx = tid; idx < 64*160; idx += 256){
            int p = idx/160, c = idx - p*160;
            Ds[p*161 + c] += bits2f(gp[idx]);
        }
    }
    __syncthreads();
    const unsigned short* Ap = (const unsigned short*)u + (pos0 + wave*16 + m)*480 + q*8;
    s8v a[15];
    #pragma unroll
    for (int kb = 0; kb < 15; ++kb) a[kb] = *(const s8v*)(Ap + kb*32);
    for (int s = 0; s < 10; ++s){
        if (s+1 < 10){
            const s8v* sp = (const s8v*)((const unsigned short*)wfc2b + (size_t)(s+1)*7680);
            for (int c = tid; c < 960; c += 256){ int row = c/60, col = (c - row*60)*8;
                *(s8v*)&Bs[(s+1)&1][row*488 + col] = sp[c]; }
        }
        f4v acc = {0.f,0.f,0.f,0.f};
        const unsigned short* Bp = &Bs[s&1][m*488 + q*8];
        #pragma unroll
        for (int kb = 0; kb < 15; ++kb) acc = MFMA(a[kb], *(const s8v*)(Bp + kb*32), acc);
        int o = s*16 + m; float bias = bfc2[o];
        #pragma unroll
        for (int r = 0; r < 4; ++r)
            Ds[(wave*16 + q*4 + r)*161 + o] += acc[r] + bias;
        __syncthreads();
    }
    float* ob = out + (size_t)bb*Cn*HWn + hw0;
    for (int idx = tid; idx < 160*64; idx += 256){
        int o = idx >> 6, p = idx & 63;
        ob[(size_t)o*HWn + p] = Ds[p*161 + o];
    }
}

extern "C" void kernel_launch(void* const* d_in, const int* in_sizes, int n_in,
                              void* d_out, int out_size, void* d_ws, size_t ws_size,
                              hipStream_t stream)
{
    (void)in_sizes; (void)n_in; (void)out_size; (void)ws_size;
    const float* x     = (const float*)d_in[0];
    const float* bn1g  = (const float*)d_in[1];
    const float* bn1b  = (const float*)d_in[2];
    const float* bn1m  = (const float*)d_in[3];
    const float* bn1v  = (const float*)d_in[4];
    const float* wt    = (const float*)d_in[5];
    const float* bt    = (const float*)d_in[6];
    const float* wb    = (const float*)d_in[7];
    const float* bb    = (const float*)d_in[8];
    const float* wr    = (const float*)d_in[9];
    const float* br    = (const float*)d_in[10];
    const float* wl    = (const float*)d_in[11];
    const float* bl    = (const float*)d_in[12];
    const float* wc    = (const float*)d_in[13];
    const float* bc    = (const float*)d_in[14];
    const float* wf1   = (const float*)d_in[15];
    const float* bf1   = (const float*)d_in[16];
    const float* bn2g  = (const float*)d_in[17];
    const float* bn2b  = (const float*)d_in[18];
    const float* bn2m  = (const float*)d_in[19];
    const float* bn2v  = (const float*)d_in[20];
    const float* wph   = (const float*)d_in[21];
    const float* bph   = (const float*)d_in[22];
    const float* wpw   = (const float*)d_in[23];
    const float* bpw   = (const float*)d_in[24];
    const float* wf2   = (const float*)d_in[25];
    const float* lng   = (const float*)d_in[26];
    const float* lnb   = (const float*)d_in[27];
    const float* wfc1  = (const float*)d_in[28];
    const float* bfc1  = (const float*)d_in[29];
    const float* wfc2  = (const float*)d_in[30];
    const float* bfc2v = (const float*)d_in[31];
    float* outp = (float*)d_out;

    // workspace layout (bytes); bf16 [Pn][160] buffer = 32,112,640 B
    const size_t PC2 = (size_t)Pn*160*2;
    char* ws = (char*)d_ws;
    bf16* hT   = (bf16*)(ws + 0*PC2);
    bf16* y5T  = (bf16*)(ws + 1*PC2);
    bf16* gT   = (bf16*)(ws + 2*PC2);
    bf16* xhT  = (bf16*)(ws + 3*PC2);
    bf16* xwT  = (bf16*)(ws + 4*PC2);
    bf16* gm   = (bf16*)(ws + 5*PC2);
    char* wsw  = ws + 6*PC2;                       // weights @ 192,675,840
    bf16*  wcat  = (bf16*)(wsw + 0);
    bf16*  wf1b  = (bf16*)(wsw + 51200);
    bf16*  wf2b  = (bf16*)(wsw + 102400);
    bf16*  wfc1b = (bf16*)(wsw + 256000);
    bf16*  wfc2b = (bf16*)(wsw + 409600);
    bf16*  wphb  = (bf16*)(wsw + 563200);
    bf16*  wpwb  = (bf16*)(wsw + 571392);
    float* bcat  = (float*)(wsw + 579584);
    float* epsv  = (float*)(wsw + 580224);
    float* eptv  = (float*)(wsw + 580864);
    bf16* uB   = (bf16*)(ws + 0);                  // [Pn][480] bf16, reuses hT/y5T/gT (dead by k7)
    // total ws use: 192.7 MB + 0.6 MB = 193.3 MB (< proven 224.8 MB)

    const int GP = Pn/64;     // 1568
    const int GS = Bn*56;     // 1792

    k0_prep<<<1134, 256, 0, stream>>>(wt, wb, wr, wl, wc, bt, bb, br, bl, bc,
                                      wf1, bf1, bn2g, bn2b, bn2m, bn2v,
                                      wf2, wfc1, wfc2, wph, wpw,
                                      wcat, wf1b, wf2b, wfc1b, wfc2b, wphb, wpwb,
                                      bcat, epsv, eptv);
    k1_bn_gelu_tr<<<GP, 256, 0, stream>>>(x, bn1g, bn1b, bn1m, bn1v, hT);
    k2_conv5     <<<GP, 256, 0, stream>>>(hT, wcat, bcat, y5T);
    k3_wf1       <<<GP, 256, 0, stream>>>(y5T, wf1b, epsv, eptv, gT);
    k4_projh     <<<GS, 256, 0, stream>>>(gT, wphb, bph, xhT);
    k5_projw     <<<GS, 256, 0, stream>>>(gT, wpwb, bpw, xwT);
    k6_wf2       <<<GP, 256, 0, stream>>>(gT, xhT, xwT, wf2b, gm);
    k7_ln_fc1    <<<GP, 256, 0, stream>>>(x, gm, lng, lnb, wfc1b, bfc1, uB);
    k8_fc2       <<<GP, 256, 0, stream>>>(uB, wfc2b, bfc2v, x, gm, outp);
}